// Round 12
// baseline (159.192 us; speedup 1.0000x reference)
//
#include <hip/hip_runtime.h>
#include <math.h>

#define NB 65
#define HOPS 256
#define RPB 8           // rows per block = rows per wave (one wave per block)
#define THREADS 64      // 8 lanes per row, 8 rows, 32 outputs per thread
#define TAPS_OFF 360    // phys size of swizzled 320-float pad region (320 + 10*4 pad)
#define RSTRIDE 492     // 360 pad(phys) + 128 taps + 4 (492%32==12 rotates rows)

// Swizzle: +4 floats of pad every 32 floats (logical pad region [0,320)).
// Logical layout per row: [0,64) zeros, [64,320) noise (2u-1); taps at [TAPS_OFF,+128).
#define PHYS(i) ((i) + (((i) >> 5) << 2))

// Zero-cost phase fence: all LDS traffic is intra-wave (DS pipe is in-order per
// wave); stop the COMPILER from moving memory ops across. No sched_barrier(0)
// walls (R8: -40%), no hardware barriers (single wave).
#define WAVE_FENCE() do { asm volatile("" ::: "memory"); __builtin_amdgcn_wave_barrier(); } while (0)

__device__ __forceinline__ void load16(float (&d)[16], const float* p) {
#pragma unroll
    for (int x = 0; x < 4; ++x) {
        float4 v = *(const float4*)(p + 4 * x);
        d[4*x] = v.x; d[4*x+1] = v.y; d[4*x+2] = v.z; d[4*x+3] = v.w;
    }
}
__device__ __forceinline__ void load16s(float (&d)[16], const float* rowbuf, int L) {
#pragma unroll
    for (int x = 0; x < 4; ++x) {
        float4 v = *(const float4*)(rowbuf + PHYS(L + 4 * x));
        d[4*x] = v.x; d[4*x+1] = v.y; d[4*x+2] = v.z; d[4*x+3] = v.w;
    }
}
// 32 outputs vs 16 taps; window = 3 16-blocks (bot,mid,top), j = 16+d-kk in [1,47]
__device__ __forceinline__ void fma32(float (&f)[32], const float (&tp)[16],
                                      const float (&b)[16], const float (&m)[16],
                                      const float (&t)[16]) {
#pragma unroll
    for (int kk = 0; kk < 16; ++kk) {
        float tv = tp[kk];
#pragma unroll
        for (int d = 0; d < 32; ++d) {
            int j = 16 + d - kk;
            float w = (j < 16) ? b[j] : (j < 32) ? m[j - 16] : t[j - 32];
            f[d] = fmaf(tv, w, f[d]);
        }
    }
}
// 8 outputs vs 16 taps; window = 2 16-blocks, j = 16+d-kk in [1,31]
__device__ __forceinline__ void fma8(float (&g)[8], const float (&tp)[16],
                                     const float (&lo)[16], const float (&hi)[16]) {
#pragma unroll
    for (int kk = 0; kk < 16; ++kk) {
        float tv = tp[kk];
#pragma unroll
        for (int d = 0; d < 8; ++d) {
            int j = 16 + d - kk;
            float w = (j < 16) ? lo[j] : hi[j - 16];
            g[d] = fmaf(tv, w, g[d]);
        }
    }
}

__global__ __launch_bounds__(THREADS, 2) void noisefilter_kernel(
    const float* __restrict__ fb,   // [65536][65]
    const float* __restrict__ nz,   // [65536][256]
    float* __restrict__ out)        // [65536][256]
{
    __shared__ float lds[RPB * RSTRIDE];
    const int lane = threadIdx.x;
    const int r    = lane >> 3;      // row within block (0..7)
    const int l8   = lane & 7;       // lane within row group
    const int t0   = l8 << 5;        // first output index (32 per thread)
    const size_t row0 = (size_t)blockIdx.x * RPB;
    float* rowbuf = &lds[r * RSTRIDE];
    float* tps = rowbuf + TAPS_OFF;

    // ---- stage amp (65 floats/row, 8 rows) ----
    {
        const float* fbw = fb + row0 * NB;
        for (int i = lane; i < RPB * NB; i += 64) {
            int rr = i / NB;
            int k  = i - rr * NB;
            lds[rr * RSTRIDE + TAPS_OFF + k] = fbw[i];
        }
    }

    // ---- prefetch noise for 8 rows (consumed after Goertzel) ----
    const float4* nz4 = (const float4*)(nz + row0 * HOPS);
    float4 nv[8];
#pragma unroll
    for (int p = 0; p < 8; ++p) nv[p] = nz4[lane + p * 64];

    WAVE_FENCE();   // amp ds_writes above, Goertzel ds_reads below

    // ---- Phase A: Goertzel, 4 frequencies per lane: n = l8 + 8m, m=0..3 ----
    float cs[4], c2s[4], k2s[4];
#pragma unroll
    for (int m = 0; m < 4; ++m) {
        float alpha = (float)(l8 + 8 * m) * 0.04908738521234052f;   // n*pi/64
        float cm = __cosf(alpha);
        cs[m] = cm;
        float c2m = fmaf(2.0f * cm, cm, -1.0f);                     // cos(2a)
        c2s[m] = c2m;
        k2s[m] = c2m + c2m;
    }
    float e1[4] = {0.f,0.f,0.f,0.f}, e2[4] = {0.f,0.f,0.f,0.f};
    float o1[4] = {0.f,0.f,0.f,0.f}, o2[4] = {0.f,0.f,0.f,0.f};
    float s32 = 0.f, a0r = 0.f, a64r;

    const float* amp = tps;          // amp staged at taps offset (overwritten later)
    a64r = amp[64];
#pragma unroll
    for (int m = 0; m < 4; ++m) {    // k = 64 (even)
        float t = a64r - e2[m]; float s = fmaf(k2s[m], e1[m], t); e2[m] = e1[m]; e1[m] = s;
    }
    s32 += a64r;
#pragma unroll
    for (int kb = 48; kb >= 0; kb -= 16) {
        float ab[16];
        load16(ab, amp + kb);
#pragma unroll
        for (int kk = 15; kk >= 0; --kk) {
            float a = ab[kk];
            if (kk & 1) {   // odd k
#pragma unroll
                for (int m = 0; m < 4; ++m) {
                    float t = a - o2[m]; float s = fmaf(k2s[m], o1[m], t); o2[m] = o1[m]; o1[m] = s;
                }
            } else {        // even k
#pragma unroll
                for (int m = 0; m < 4; ++m) {
                    float t = a - e2[m]; float s = fmaf(k2s[m], e1[m], t); e2[m] = e1[m]; e1[m] = s;
                }
                if ((kk >> 1) & 1) s32 -= a; else s32 += a;
            }
        }
        if (kb == 0) a0r = ab[0];
    }

    const float pm = (l8 & 1) ? -1.f : 1.f;       // (-1)^n, n = l8+8m
    const float corr = fmaf(pm, a64r, a0r);
    const float inv = 1.0f / 256.0f;
#pragma unroll
    for (int m = 0; m < 4; ++m) {
        int n = l8 + 8 * m;
        float E  = fmaf(-c2s[m], e2[m], e1[m]);
        float O  = cs[m] * (o1[m] - o2[m]);
        float G  = fmaf(2.f, E + O, -corr);
        float Gm = fmaf(2.f, E - O, -corr);
        float T  = G  * (1.0f + cs[m]) * inv;
        float Tm = Gm * (1.0f - cs[m]) * inv;
        tps[n] = T;
        tps[64 - n] = Tm;
        if (n >= 1) { tps[128 - n] = T; tps[64 + n] = Tm; }
    }
    if (l8 == 0) {   // n = 32
        float G32 = fmaf(2.f, s32, -(a0r + a64r));
        float T32 = G32 * inv;
        tps[32] = T32;
        tps[96] = T32;
    }

    // ---- zero logical [0,64) of own row (two float4 per lane) ----
    *(float4*)(rowbuf + PHYS(8 * l8))     = make_float4(0.f, 0.f, 0.f, 0.f);
    *(float4*)(rowbuf + PHYS(8 * l8 + 4)) = make_float4(0.f, 0.f, 0.f, 0.f);

    // ---- store noise (2u-1) into logical [64,320) of the 8 rows ----
#pragma unroll
    for (int p = 0; p < 8; ++p) {
        float4 v = nv[p];
        int o = (lane << 2) + 64;           // row p, offset 4*lane+64
        *(float4*)(&lds[p * RSTRIDE + PHYS(o)]) =
            make_float4(fmaf(2.f, v.x, -1.f), fmaf(2.f, v.y, -1.f),
                        fmaf(2.f, v.z, -1.f), fmaf(2.f, v.w, -1.f));
    }

    WAVE_FENCE();   // tap/zero/noise ds_writes above, C1/C2 ds_reads below

    // ---- Phase C1: taps 0..63, 32 outputs/thread, sliding 3-block window ----
    // out[t] = sum_k tps[k]*S[64+t-k]; j = 16+d-kk in [1,47], blocks [B,B+48),
    // B = t0+48-16*kc. In-place block rotation (3 slots).
    float f[32];
#pragma unroll
    for (int d = 0; d < 32; ++d) f[d] = 0.f;
    {
        float W0[16], W1[16], W2[16], tp[16];
        const int b0 = t0 + 48;
        load16s(W0, rowbuf, b0);
        load16s(W1, rowbuf, b0 + 16);
        load16s(W2, rowbuf, b0 + 32);
        load16(tp, tps + 0);   fma32(f, tp, W0, W1, W2);   // kc=0: [t0+48,t0+96)
        load16s(W2, rowbuf, b0 - 16);
        load16(tp, tps + 16);  fma32(f, tp, W2, W0, W1);   // kc=1: [t0+32,t0+80)
        load16s(W1, rowbuf, b0 - 32);
        load16(tp, tps + 32);  fma32(f, tp, W1, W2, W0);   // kc=2: [t0+16,t0+64)
        load16s(W0, rowbuf, b0 - 48);
        load16(tp, tps + 48);  fma32(f, tp, W0, W1, W2);   // kc=3: [t0,   t0+48)
    }

    // ---- Phase C2: taps 64..127 (circular tail), outputs t>=192 only.
    //      Dense: lane l8 computes partials for t' = 192+8*l8+{0..7}.
    //      S-idx = 64+8*l8+d-16*kc-kk; blocks [B',B'+32), B' = 48+8*l8-16*kc.
    float g[8];
#pragma unroll
    for (int d = 0; d < 8; ++d) g[d] = 0.f;
    {
        float V0[16], V1[16], t2[16];
        const int Bb = 48 + 8 * l8;
        load16s(V0, rowbuf, Bb);
        load16s(V1, rowbuf, Bb + 16);
        load16(t2, tps + 64);   fma8(g, t2, V0, V1);       // kc=0
        load16s(V1, rowbuf, Bb - 16);
        load16(t2, tps + 80);   fma8(g, t2, V1, V0);       // kc=1
        load16s(V0, rowbuf, Bb - 32);
        load16(t2, tps + 96);   fma8(g, t2, V0, V1);       // kc=2
        load16s(V1, rowbuf, Bb - 48);
        load16(t2, tps + 112);  fma8(g, t2, V1, V0);       // kc=3
    }
    // exchange partials via row scratch (overwrites taps[64..128) — all tap
    // reads done; same-wave DS ops are in-order, no barrier needed)
    *(float4*)(tps + 64 + 8 * l8)     = make_float4(g[0], g[1], g[2], g[3]);
    *(float4*)(tps + 64 + 8 * l8 + 4) = make_float4(g[4], g[5], g[6], g[7]);
    if (l8 >= 6) {
        const float* sc = tps + 64 + ((l8 - 6) << 5);
#pragma unroll
        for (int x = 0; x < 8; ++x) {
            float4 v = *(const float4*)(sc + 4 * x);
            f[4*x]   += v.x; f[4*x+1] += v.y;
            f[4*x+2] += v.z; f[4*x+3] += v.w;
        }
    }

    // ---- store 32 outputs ----
    float* op = out + (row0 + r) * HOPS + t0;
#pragma unroll
    for (int x = 0; x < 8; ++x)
        *(float4*)(op + 4 * x) = make_float4(f[4*x], f[4*x+1], f[4*x+2], f[4*x+3]);
}

extern "C" void kernel_launch(void* const* d_in, const int* in_sizes, int n_in,
                              void* d_out, int out_size, void* d_ws, size_t ws_size,
                              hipStream_t stream) {
    const float* fb = (const float*)d_in[0];
    const float* nz = (const float*)d_in[1];
    float* o = (float*)d_out;
    const int rows = 16 * 4096;              // 65536
    noisefilter_kernel<<<dim3(rows / RPB), dim3(THREADS), 0, stream>>>(fb, nz, o);
}

// Round 13
// 147.988 us; speedup vs baseline: 1.0757x; 1.0757x over previous
//
#include <hip/hip_runtime.h>
#include <math.h>

#define NB 65
#define HOPS 256
#define RPB 4           // rows per block = one wave; waves fully independent
#define THREADS 64      // 16 lanes per row, 4 rows per wave
#define TAPS_OFF 360    // phys size of swizzled 320-float pad region (320 + 10*4 pad)
#define RSTRIDE 492     // 360 pad(phys) + 128 taps + 4 (492%32==12 rotates rows)

// Swizzle: +4 floats of pad every 32 floats (logical pad region [0,320)).
// Logical layout per row: [0,64) zeros, [64,320) noise (2u-1); taps at [TAPS_OFF,+128).
// (R1/R9-measured best; R12 retile regressed via spills -> reverted.)
#define PHYS(i) ((i) + (((i) >> 5) << 2))

// Zero-cost phase fence: all LDS traffic is intra-wave (DS pipe is in-order per
// wave); stop the COMPILER from moving memory ops across. No sched_barrier(0)
// walls (R8: -40%), no hardware barriers (single wave).
#define WAVE_FENCE() do { asm volatile("" ::: "memory"); __builtin_amdgcn_wave_barrier(); } while (0)

typedef float v2f __attribute__((ext_vector_type(2)));

__device__ __forceinline__ void load16(float (&d)[16], const float* p) {
#pragma unroll
    for (int x = 0; x < 4; ++x) {
        float4 v = *(const float4*)(p + 4 * x);
        d[4*x] = v.x; d[4*x+1] = v.y; d[4*x+2] = v.z; d[4*x+3] = v.w;
    }
}
// 16 floats as 8 aligned float2 pairs (pairs (0,1),(2,3),... of the window)
__device__ __forceinline__ void load16sv(v2f (&d)[8], const float* rowbuf, int L) {
#pragma unroll
    for (int x = 0; x < 4; ++x) {
        float4 v = *(const float4*)(rowbuf + PHYS(L + 4 * x));
        d[2*x]   = v2f{v.x, v.y};
        d[2*x+1] = v2f{v.z, v.w};
    }
}
// 20 floats as 10 pairs
__device__ __forceinline__ void load20sv(v2f (&d)[10], const float* rowbuf, int L) {
#pragma unroll
    for (int x = 0; x < 5; ++x) {
        float4 v = *(const float4*)(rowbuf + PHYS(L + 4 * x));
        d[2*x]   = v2f{v.x, v.y};
        d[2*x+1] = v2f{v.z, v.w};
    }
}

// Packed sliding-window FMA: 16 outputs (8 v2f pairs) vs 16 taps.
// w[j] = j<16 ? lo[j] : hi[j-16], j = 16+d-kk in [1,31].
// kk even -> output pair (d,d+1) uses aligned window pair (w[j],w[j+1]) ->
// single v_pk_fma_f32, no moves. kk odd -> misaligned, scalar (opsel cannot
// source two halves from different registers).
__device__ __forceinline__ void fma16p(v2f (&f)[8], const float (&tp)[16],
                                       const v2f (&lo)[8], const v2f (&hi)[8]) {
#pragma unroll
    for (int kk = 0; kk < 16; ++kk) {
        float t = tp[kk];
        if ((kk & 1) == 0) {
            v2f tv = {t, t};
#pragma unroll
            for (int p = 0; p < 8; ++p) {
                int j = 16 + 2 * p - kk;           // even, in [2,30]
                v2f w = (j < 16) ? lo[j >> 1] : hi[(j - 16) >> 1];
                f[p] = __builtin_elementwise_fma(tv, w, f[p]);
            }
        } else {
#pragma unroll
            for (int d = 0; d < 16; ++d) {
                int j = 16 + d - kk;               // in [1,31]
                float w = (j < 16) ? lo[j >> 1][j & 1] : hi[(j - 16) >> 1][j & 1];
                f[d >> 1][d & 1] = fmaf(t, w, f[d >> 1][d & 1]);
            }
        }
    }
}
// Packed 4-output variant for C2: W covers 20 floats (10 pairs), j in [1,19].
__device__ __forceinline__ void fma4p(v2f (&g)[2], const float (&tp)[16],
                                      const v2f (&W)[10]) {
#pragma unroll
    for (int kk = 0; kk < 16; ++kk) {
        float t = tp[kk];
        if ((kk & 1) == 0) {
            v2f tv = {t, t};
#pragma unroll
            for (int p = 0; p < 2; ++p) {
                int j = 16 + 2 * p - kk;           // even, in [2,18]
                g[p] = __builtin_elementwise_fma(tv, W[j >> 1], g[p]);
            }
        } else {
#pragma unroll
            for (int d = 0; d < 4; ++d) {
                int j = 16 + d - kk;               // in [1,19]
                g[d >> 1][d & 1] = fmaf(t, W[j >> 1][j & 1], g[d >> 1][d & 1]);
            }
        }
    }
}

__global__ __launch_bounds__(THREADS, 4) void noisefilter_kernel(
    const float* __restrict__ fb,   // [65536][65]
    const float* __restrict__ nz,   // [65536][256]
    float* __restrict__ out)        // [65536][256]
{
    __shared__ float lds[RPB * RSTRIDE];
    const int tid  = threadIdx.x;
    const int lane = tid;            // single wave per block
    const int r    = tid >> 4;       // row within block (0..3)
    const int l16  = tid & 15;       // lane within row group
    const int t0   = l16 << 4;       // first output index of this thread
    const size_t row0 = (size_t)blockIdx.x * RPB;
    float* rowbuf = &lds[r * RSTRIDE];

    // ---- stage amp (65 floats/row) for the wave's 4 rows ----
    {
        const float* fbw = fb + row0 * NB;
        for (int i = lane; i < RPB * NB; i += 64) {
            int rr = i / NB;
            int k  = i - rr * NB;
            lds[rr * RSTRIDE + TAPS_OFF + k] = fbw[i];
        }
    }

    // ---- prefetch noise for the wave's 4 rows (consumed after Goertzel) ----
    const float4* nz4 = (const float4*)(nz + row0 * HOPS);
    float4 nv[4];
#pragma unroll
    for (int p = 0; p < 4; ++p) nv[p] = nz4[lane + p * 64];

    WAVE_FENCE();   // amp ds_writes above, Goertzel ds_reads below (intra-wave, in-order)

    // ---- Phase A: Goertzel, A/B frequency pair PACKED into v2f lanes ----
    const float alphaA = (float)l16 * 0.04908738521234052f;          // pi/64 * nA
    const float alphaB = alphaA + 0.7853981633974483f;               // + pi/4
    const float cA = __cosf(alphaA), cB = __cosf(alphaB);
    const float c2A = fmaf(2.0f * cA, cA, -1.0f);                    // cos(2a)
    const float c2B = fmaf(2.0f * cB, cB, -1.0f);
    const v2f k2v = {c2A + c2A, c2B + c2B};

    v2f e1 = {0.f, 0.f}, e2 = {0.f, 0.f}, o1 = {0.f, 0.f}, o2 = {0.f, 0.f};
    float s32 = 0.f, a0r = 0.f, a64r;

    const float* amp = rowbuf + TAPS_OFF;
    {   // k = 64 (even chain)
        float a = amp[64];
        a64r = a;
        v2f av = {a, a};
        v2f t = av - e2; v2f s = __builtin_elementwise_fma(k2v, e1, t); e2 = e1; e1 = s;
        s32 += a;
    }
#pragma unroll
    for (int kb = 48; kb >= 0; kb -= 16) {
        float ab[16];
        load16(ab, amp + kb);
#pragma unroll
        for (int kk = 15; kk >= 0; --kk) {
            float a = ab[kk];
            v2f av = {a, a};
            if (kk & 1) {   // odd k
                v2f t = av - o2; v2f s = __builtin_elementwise_fma(k2v, o1, t); o2 = o1; o1 = s;
            } else {        // even k
                v2f t = av - e2; v2f s = __builtin_elementwise_fma(k2v, e1, t); e2 = e1; e1 = s;
                if ((kk >> 1) & 1) s32 -= a; else s32 += a;
            }
        }
        if (kb == 0) a0r = ab[0];
    }

    const float EA = fmaf(-c2A, e2[0], e1[0]);
    const float OA = cA * (o1[0] - o2[0]);
    const float EB = fmaf(-c2B, e2[1], e1[1]);
    const float OB = cB * (o1[1] - o2[1]);
    const float pm = (l16 & 1) ? -1.f : 1.f;      // (-1)^n
    const float corr = fmaf(pm, a64r, a0r);
    const float inv = 1.0f / 256.0f;
    float* tps = rowbuf + TAPS_OFF;

    {   // pair A: n = l16, mirror 64-l16
        float GA  = fmaf(2.f, EA + OA, -corr);
        float GAm = fmaf(2.f, EA - OA, -corr);
        float TA  = GA  * (1.0f + cA) * inv;
        float TAm = GAm * (1.0f - cA) * inv;
        tps[l16] = TA;
        tps[64 - l16] = TAm;
        if (l16 >= 1) { tps[128 - l16] = TA; tps[64 + l16] = TAm; }
    }
    {   // pair B: n = 16+l16, mirror 48-l16
        float GB  = fmaf(2.f, EB + OB, -corr);
        float GBm = fmaf(2.f, EB - OB, -corr);
        float TB  = GB  * (1.0f + cB) * inv;
        float TBm = GBm * (1.0f - cB) * inv;
        tps[16 + l16] = TB;  tps[112 - l16] = TB;
        tps[48 - l16] = TBm; tps[80 + l16]  = TBm;
    }
    if (l16 == 0) {   // n = 32 (single lane: avoid 16-way same-address write)
        float G32 = fmaf(2.f, s32, -(a0r + a64r));
        float T32 = G32 * inv;
        tps[32] = T32;
        tps[96] = T32;
    }

    // ---- zero logical [0,64) of own row (one float4 per lane) ----
    *(float4*)(rowbuf + PHYS(4 * l16)) = make_float4(0.f, 0.f, 0.f, 0.f);

    // ---- store noise (2u-1) into logical [64,320) of the wave's rows ----
#pragma unroll
    for (int p = 0; p < 4; ++p) {
        float4 v = nv[p];
        int o = (lane << 2) + 64;           // idx = lane + 64p -> row p, offset 4*lane+64
        *(float4*)(&lds[p * RSTRIDE + PHYS(o)]) =
            make_float4(fmaf(2.f, v.x, -1.f), fmaf(2.f, v.y, -1.f),
                        fmaf(2.f, v.z, -1.f), fmaf(2.f, v.w, -1.f));
    }

    WAVE_FENCE();   // tap/zero/noise ds_writes above, C1/C2 ds_reads below (intra-wave)

    // ---- Phase C1: taps 0..63 (delays 0..63), all 256 outputs, sliding window,
    //      packed accumulator (8 x v2f = 16 outputs) ----
    v2f f[8];
#pragma unroll
    for (int p = 0; p < 8; ++p) f[p] = v2f{0.f, 0.f};
    {
        v2f X[8], Y[8], Z[8];
        float tp[16];
        const int b0 = t0 + 48;
        load16sv(X, rowbuf, b0);      load16sv(Y, rowbuf, b0 + 16);
        load16(tp, tps + 0);   fma16p(f, tp, X, Y);
        load16sv(Z, rowbuf, b0 - 16);
        load16(tp, tps + 16);  fma16p(f, tp, Z, X);
        load16sv(Y, rowbuf, b0 - 32);
        load16(tp, tps + 32);  fma16p(f, tp, Y, Z);
        load16sv(X, rowbuf, b0 - 48);
        load16(tp, tps + 48);  fma16p(f, tp, X, Y);
    }

    // ---- Phase C2: tail taps 64..127 (delays 192..255) -> only outputs t>=192.
    //      Dense assignment: lane l16 computes partials for t' = 192+4*l16+{0..3}.
    v2f g[2] = {v2f{0.f, 0.f}, v2f{0.f, 0.f}};
#pragma unroll
    for (int c = 0; c < 4; ++c) {
        v2f W[10];
        load20sv(W, rowbuf, 48 + 4 * l16 - 16 * c);
        float tp2[16];
        load16(tp2, tps + 64 + 16 * c);
        fma4p(g, tp2, W);
    }
    // exchange partials via row scratch (overwrites taps[64..128) — all reads done;
    // same-wave DS ops are in-order, no barrier needed)
    *(float4*)(tps + 64 + 4 * l16) = make_float4(g[0][0], g[0][1], g[1][0], g[1][1]);
    if (l16 >= 12) {
        const float* sc = tps + 64 + ((l16 - 12) << 4);
#pragma unroll
        for (int x = 0; x < 4; ++x) {
            float4 v = *(const float4*)(sc + 4 * x);
            f[2*x]   += v2f{v.x, v.y};
            f[2*x+1] += v2f{v.z, v.w};
        }
    }

    // ---- store ----
    float* op = out + (row0 + r) * HOPS + t0;
#pragma unroll
    for (int x = 0; x < 4; ++x)
        *(float4*)(op + 4 * x) = make_float4(f[2*x][0], f[2*x][1], f[2*x+1][0], f[2*x+1][1]);
}

extern "C" void kernel_launch(void* const* d_in, const int* in_sizes, int n_in,
                              void* d_out, int out_size, void* d_ws, size_t ws_size,
                              hipStream_t stream) {
    const float* fb = (const float*)d_in[0];
    const float* nz = (const float*)d_in[1];
    float* o = (float*)d_out;
    const int rows = 16 * 4096;              // 65536
    noisefilter_kernel<<<dim3(rows / RPB), dim3(THREADS), 0, stream>>>(fb, nz, o);
}

// Round 14
// 143.743 us; speedup vs baseline: 1.1075x; 1.0295x over previous
//
#include <hip/hip_runtime.h>
#include <math.h>

#define NB 65
#define HOPS 256
#define RPB 16          // rows per block: 4 waves x 4 rows, waves fully independent
#define THREADS 256
#define TAPS_OFF 360    // phys size of swizzled 320-float pad region (320 + 10*4 pad)
#define RSTRIDE 492     // 360 pad(phys) + 128 taps + 4 (492%32==12 rotates rows)

// Swizzle: +4 floats of pad every 32 floats (logical pad region [0,320)).
// Logical layout per row: [0,64) zeros, [64,320) noise (2u-1); taps at [TAPS_OFF,+128).
#define PHYS(i) ((i) + (((i) >> 5) << 2))

// Zero-cost phase fence: all LDS traffic is intra-wave (DS pipe is in-order per
// wave); stop the COMPILER from moving memory ops across. No __syncthreads:
// each wave touches only its own 4 rows.
#define WAVE_FENCE() do { asm volatile("" ::: "memory"); __builtin_amdgcn_wave_barrier(); } while (0)

typedef float v2f __attribute__((ext_vector_type(2)));

__device__ __forceinline__ void load16(float (&d)[16], const float* p) {
#pragma unroll
    for (int x = 0; x < 4; ++x) {
        float4 v = *(const float4*)(p + 4 * x);
        d[4*x] = v.x; d[4*x+1] = v.y; d[4*x+2] = v.z; d[4*x+3] = v.w;
    }
}
// 16 floats as 8 aligned float2 pairs
__device__ __forceinline__ void load16sv(v2f (&d)[8], const float* rowbuf, int L) {
#pragma unroll
    for (int x = 0; x < 4; ++x) {
        float4 v = *(const float4*)(rowbuf + PHYS(L + 4 * x));
        d[2*x]   = v2f{v.x, v.y};
        d[2*x+1] = v2f{v.z, v.w};
    }
}
// 20 floats as 10 pairs
__device__ __forceinline__ void load20sv(v2f (&d)[10], const float* rowbuf, int L) {
#pragma unroll
    for (int x = 0; x < 5; ++x) {
        float4 v = *(const float4*)(rowbuf + PHYS(L + 4 * x));
        d[2*x]   = v2f{v.x, v.y};
        d[2*x+1] = v2f{v.z, v.w};
    }
}

// Packed sliding-window FMA: 16 outputs (8 v2f pairs) vs 16 taps.
// kk even -> aligned window pair -> v_pk_fma_f32; kk odd -> scalar.
__device__ __forceinline__ void fma16p(v2f (&f)[8], const float (&tp)[16],
                                       const v2f (&lo)[8], const v2f (&hi)[8]) {
#pragma unroll
    for (int kk = 0; kk < 16; ++kk) {
        float t = tp[kk];
        if ((kk & 1) == 0) {
            v2f tv = {t, t};
#pragma unroll
            for (int p = 0; p < 8; ++p) {
                int j = 16 + 2 * p - kk;           // even, in [2,30]
                v2f w = (j < 16) ? lo[j >> 1] : hi[(j - 16) >> 1];
                f[p] = __builtin_elementwise_fma(tv, w, f[p]);
            }
        } else {
#pragma unroll
            for (int d = 0; d < 16; ++d) {
                int j = 16 + d - kk;               // in [1,31]
                float w = (j < 16) ? lo[j >> 1][j & 1] : hi[(j - 16) >> 1][j & 1];
                f[d >> 1][d & 1] = fmaf(t, w, f[d >> 1][d & 1]);
            }
        }
    }
}
// Packed 4-output variant for C2: W covers 20 floats (10 pairs), j in [1,19].
__device__ __forceinline__ void fma4p(v2f (&g)[2], const float (&tp)[16],
                                      const v2f (&W)[10]) {
#pragma unroll
    for (int kk = 0; kk < 16; ++kk) {
        float t = tp[kk];
        if ((kk & 1) == 0) {
            v2f tv = {t, t};
#pragma unroll
            for (int p = 0; p < 2; ++p) {
                int j = 16 + 2 * p - kk;           // even, in [2,18]
                g[p] = __builtin_elementwise_fma(tv, W[j >> 1], g[p]);
            }
        } else {
#pragma unroll
            for (int d = 0; d < 4; ++d) {
                int j = 16 + d - kk;               // in [1,19]
                g[d >> 1][d & 1] = fmaf(t, W[j >> 1][j & 1], g[d >> 1][d & 1]);
            }
        }
    }
}

__global__ __launch_bounds__(THREADS, 4) void noisefilter_kernel(
    const float* __restrict__ fb,   // [65536][65]
    const float* __restrict__ nz,   // [65536][256]
    float* __restrict__ out)        // [65536][256]
{
    __shared__ float lds[RPB * RSTRIDE];
    const int tid  = threadIdx.x;
    const int wv   = tid >> 6;       // wave 0..3; wave owns rows 4wv..4wv+3
    const int lane = tid & 63;
    const int rl   = lane >> 4;      // row within wave (0..3)
    const int l16  = lane & 15;      // lane within row group
    const int t0   = l16 << 4;       // first output index of this thread
    const size_t row0 = (size_t)blockIdx.x * RPB;
    float* rowbuf = &lds[(4 * wv + rl) * RSTRIDE];

    // ---- stage amp (65 floats/row) — each wave stages ITS OWN 4 rows ----
    {
        const float* fbw = fb + (row0 + 4 * wv) * NB;
        float* base = &lds[(4 * wv) * RSTRIDE];
        for (int i = lane; i < 4 * NB; i += 64) {
            int rr = i / NB;
            int k  = i - rr * NB;
            base[rr * RSTRIDE + TAPS_OFF + k] = fbw[i];
        }
    }

    // ---- prefetch noise for own wave's 4 rows (consumed after Goertzel) ----
    const float4* nz4 = (const float4*)(nz + (row0 + 4 * wv) * HOPS);
    float4 nv[4];
#pragma unroll
    for (int p = 0; p < 4; ++p) nv[p] = nz4[lane + p * 64];

    WAVE_FENCE();   // amp ds_writes above, Goertzel ds_reads below (intra-wave, in-order)

    // ---- Phase A: Goertzel, A/B frequency pair PACKED into v2f lanes ----
    const float alphaA = (float)l16 * 0.04908738521234052f;          // pi/64 * nA
    const float alphaB = alphaA + 0.7853981633974483f;               // + pi/4
    const float cA = __cosf(alphaA), cB = __cosf(alphaB);
    const float c2A = fmaf(2.0f * cA, cA, -1.0f);                    // cos(2a)
    const float c2B = fmaf(2.0f * cB, cB, -1.0f);
    const v2f k2v = {c2A + c2A, c2B + c2B};

    v2f e1 = {0.f, 0.f}, e2 = {0.f, 0.f}, o1 = {0.f, 0.f}, o2 = {0.f, 0.f};
    float s32 = 0.f, a0r = 0.f, a64r;

    const float* amp = rowbuf + TAPS_OFF;
    {   // k = 64 (even chain)
        float a = amp[64];
        a64r = a;
        v2f av = {a, a};
        v2f t = av - e2; v2f s = __builtin_elementwise_fma(k2v, e1, t); e2 = e1; e1 = s;
        s32 += a;
    }
#pragma unroll
    for (int kb = 48; kb >= 0; kb -= 16) {
        float ab[16];
        load16(ab, amp + kb);
#pragma unroll
        for (int kk = 15; kk >= 0; --kk) {
            float a = ab[kk];
            v2f av = {a, a};
            if (kk & 1) {   // odd k
                v2f t = av - o2; v2f s = __builtin_elementwise_fma(k2v, o1, t); o2 = o1; o1 = s;
            } else {        // even k
                v2f t = av - e2; v2f s = __builtin_elementwise_fma(k2v, e1, t); e2 = e1; e1 = s;
                if ((kk >> 1) & 1) s32 -= a; else s32 += a;
            }
        }
        if (kb == 0) a0r = ab[0];
    }

    const float EA = fmaf(-c2A, e2[0], e1[0]);
    const float OA = cA * (o1[0] - o2[0]);
    const float EB = fmaf(-c2B, e2[1], e1[1]);
    const float OB = cB * (o1[1] - o2[1]);
    const float pm = (l16 & 1) ? -1.f : 1.f;      // (-1)^n
    const float corr = fmaf(pm, a64r, a0r);
    const float inv = 1.0f / 256.0f;
    float* tps = rowbuf + TAPS_OFF;

    {   // pair A: n = l16, mirror 64-l16
        float GA  = fmaf(2.f, EA + OA, -corr);
        float GAm = fmaf(2.f, EA - OA, -corr);
        float TA  = GA  * (1.0f + cA) * inv;
        float TAm = GAm * (1.0f - cA) * inv;
        tps[l16] = TA;
        tps[64 - l16] = TAm;
        if (l16 >= 1) { tps[128 - l16] = TA; tps[64 + l16] = TAm; }
    }
    {   // pair B: n = 16+l16, mirror 48-l16
        float GB  = fmaf(2.f, EB + OB, -corr);
        float GBm = fmaf(2.f, EB - OB, -corr);
        float TB  = GB  * (1.0f + cB) * inv;
        float TBm = GBm * (1.0f - cB) * inv;
        tps[16 + l16] = TB;  tps[112 - l16] = TB;
        tps[48 - l16] = TBm; tps[80 + l16]  = TBm;
    }
    if (l16 == 0) {   // n = 32 (single lane: avoid 16-way same-address write)
        float G32 = fmaf(2.f, s32, -(a0r + a64r));
        float T32 = G32 * inv;
        tps[32] = T32;
        tps[96] = T32;
    }

    // ---- zero logical [0,64) of own row (one float4 per lane) ----
    *(float4*)(rowbuf + PHYS(4 * l16)) = make_float4(0.f, 0.f, 0.f, 0.f);

    // ---- store noise (2u-1) into logical [64,320) of own wave's rows ----
#pragma unroll
    for (int p = 0; p < 4; ++p) {
        float4 v = nv[p];
        int o = (lane << 2) + 64;           // row 4wv+p, offset 4*lane+64
        *(float4*)(&lds[(4 * wv + p) * RSTRIDE + PHYS(o)]) =
            make_float4(fmaf(2.f, v.x, -1.f), fmaf(2.f, v.y, -1.f),
                        fmaf(2.f, v.z, -1.f), fmaf(2.f, v.w, -1.f));
    }

    WAVE_FENCE();   // tap/zero/noise ds_writes above, C1/C2 ds_reads below (intra-wave)

    // ---- Phase C1: taps 0..63 (delays 0..63), all 256 outputs, sliding window,
    //      packed accumulator (8 x v2f = 16 outputs) ----
    v2f f[8];
#pragma unroll
    for (int p = 0; p < 8; ++p) f[p] = v2f{0.f, 0.f};
    {
        v2f X[8], Y[8], Z[8];
        float tp[16];
        const int b0 = t0 + 48;
        load16sv(X, rowbuf, b0);      load16sv(Y, rowbuf, b0 + 16);
        load16(tp, tps + 0);   fma16p(f, tp, X, Y);
        load16sv(Z, rowbuf, b0 - 16);
        load16(tp, tps + 16);  fma16p(f, tp, Z, X);
        load16sv(Y, rowbuf, b0 - 32);
        load16(tp, tps + 32);  fma16p(f, tp, Y, Z);
        load16sv(X, rowbuf, b0 - 48);
        load16(tp, tps + 48);  fma16p(f, tp, X, Y);
    }

    // ---- Phase C2: tail taps 64..127 (delays 192..255) -> only outputs t>=192.
    //      Dense assignment: lane l16 computes partials for t' = 192+4*l16+{0..3}.
    v2f g[2] = {v2f{0.f, 0.f}, v2f{0.f, 0.f}};
#pragma unroll
    for (int c = 0; c < 4; ++c) {
        v2f W[10];
        load20sv(W, rowbuf, 48 + 4 * l16 - 16 * c);
        float tp2[16];
        load16(tp2, tps + 64 + 16 * c);
        fma4p(g, tp2, W);
    }
    // exchange partials via row scratch (overwrites taps[64..128) — all reads done;
    // same-wave DS ops are in-order, no barrier needed)
    *(float4*)(tps + 64 + 4 * l16) = make_float4(g[0][0], g[0][1], g[1][0], g[1][1]);
    if (l16 >= 12) {
        const float* sc = tps + 64 + ((l16 - 12) << 4);
#pragma unroll
        for (int x = 0; x < 4; ++x) {
            float4 v = *(const float4*)(sc + 4 * x);
            f[2*x]   += v2f{v.x, v.y};
            f[2*x+1] += v2f{v.z, v.w};
        }
    }

    // ---- store ----
    float* op = out + (row0 + 4 * wv + rl) * HOPS + t0;
#pragma unroll
    for (int x = 0; x < 4; ++x)
        *(float4*)(op + 4 * x) = make_float4(f[2*x][0], f[2*x][1], f[2*x+1][0], f[2*x+1][1]);
}

extern "C" void kernel_launch(void* const* d_in, const int* in_sizes, int n_in,
                              void* d_out, int out_size, void* d_ws, size_t ws_size,
                              hipStream_t stream) {
    const float* fb = (const float*)d_in[0];
    const float* nz = (const float*)d_in[1];
    float* o = (float*)d_out;
    const int rows = 16 * 4096;              // 65536
    noisefilter_kernel<<<dim3(rows / RPB), dim3(THREADS), 0, stream>>>(fb, nz, o);
}